// Round 15
// baseline (470.155 us; speedup 1.0000x reference)
//
#include <hip/hip_runtime.h>
#include <hip/hip_bf16.h>
#include <stdint.h>

using f32x16 = __attribute__((ext_vector_type(16))) float;
using short8 = __attribute__((ext_vector_type(8))) short;

#define C2LOG2E 2.8853900817779268f   // 2*log2(e)

static __device__ __forceinline__ unsigned cvt_pk_bf16(float lo, float hi) {
  unsigned r;
  asm("v_cvt_pk_bf16_f32 %0, %1, %2" : "=v"(r) : "v"(lo), "v"(hi));
  return r;
}

// butterfly add stage via DPP (VALU, no DS); ctrl is a template constant.
template <int CTRL>
static __device__ __forceinline__ float dpp_add(float v) {
  int x = __builtin_amdgcn_update_dpp(0, __float_as_int(v), CTRL, 0xF, 0xF, true);
  return v + __int_as_float(x);
}
#define DPP_XOR1 0xB1   // quad_perm [1,0,3,2]
#define DPP_XOR2 0x4E   // quad_perm [2,3,0,1]
#define DPP_XOR4 0x141  // row_half_mirror
#define DPP_XOR8 0x140  // row_mirror

// magic multipliers indexed by DIVISOR d (1..8): q = (rr * M[d]) >> 16, exact for rr<2^10
__device__ static const unsigned kMagicDiv[9] = {0u, 65536u, 32768u, 21846u, 16384u,
                                                 13108u, 10923u, 9363u, 8192u};

// ---------------------------------------------------------------- prep ------
// Pack x and Wp into 32x32x16-MFMA fragment-linear bf16 layouts.
// 1KB block = [32 rows x 16 k] bf16: byte(rc,kk) = ((kk>>3)*32 + rc)*16 + (kk&7)*2
// xfrag : per b: blocks (mt 0..7, ks 0..15) of x[b][mt*32+row][ks*16+kk]
// wpfrag: blocks (et 0..7, ks 0..15) of Wp[ks*16+kk][et*32+col]
__global__ __launch_bounds__(256) void k_prep(const float* __restrict__ x,
                                              const float* __restrict__ Wp,
                                              unsigned int* __restrict__ xfrag,
                                              unsigned int* __restrict__ wpfrag) {
  const int bid = blockIdx.x, t = threadIdx.x;
  const int half = t >> 7, dpair = (t >> 5) & 3, rc = t & 31;
  const int kk = half * 8 + dpair * 2;
  if (bid < 1024) {
    const int b = bid >> 7, mt = (bid >> 4) & 7, ks = bid & 15;
    const int m = mt * 32 + rc;
    const int k = ks * 16 + kk;
    float2 v = *(const float2*)(x + (size_t)(b * 256 + m) * 256 + k);
    xfrag[(size_t)b * 32768 + ((mt * 16 + ks) << 8) + half * 128 + rc * 4 + dpair] =
        cvt_pk_bf16(v.x, v.y);
  } else {
    const int b2 = bid - 1024;                 // 0..127
    const int et = b2 >> 4, ks = b2 & 15;
    const int e = et * 32 + rc;
    const int k = ks * 16 + kk;
    float v0 = Wp[(size_t)k * 256 + e];
    float v1 = Wp[(size_t)(k + 1) * 256 + e];
    wpfrag[((et * 16 + ks) << 8) + half * 128 + rc * 4 + dpair] = cvt_pk_bf16(v0, v1);
  }
}

// --------------------------------------------------------------- scores -----
// Full-e items (b, n, mt), mt >= n>>5: 9216 total.  Block = 512 thr / 8 waves;
// full Wp (128 KB) in LDS -> occupancy LDS-CAPPED at 1 block/CU (R14 lesson:
// TLP is not the lever here).  THIS round: per-et epilogue folding — hold
// pp[16] A-frags in V (64 regs), one acc f32x16 per et (released immediately
// into p[16] after its 16-MFMA chain).  epilogue(et) is register-independent
// of the MFMA/DS stream of et+1 -> compiler interleaves them WITHIN the wave,
// hiding the ~35us of post-MFMA serial epilogue observed in R14.
__global__ __launch_bounds__(512, 2) void k_scores(
    const unsigned int* __restrict__ xfrag, const unsigned int* __restrict__ wpfrag,
    const float* __restrict__ bp, const float* __restrict__ watt,
    float* __restrict__ sp) {
  __shared__ unsigned char wplds[131072];

  const int tid = threadIdx.x;
  const int l = tid & 63, w = tid >> 6;          // w in [0,8)
  const int c = l & 31, hi = l >> 5;

  // stage full Wp frag (128 KB) linearly, zero VALU (8 waves x 16 it x 1KB)
  {
    const unsigned char* src = (const unsigned char*)wpfrag;
    #pragma unroll
    for (int it = 0; it < 16; ++it) {
      __builtin_amdgcn_global_load_lds(
          (const __attribute__((address_space(1))) unsigned int*)(src + it * 8192 + w * 1024 + l * 16),
          (__attribute__((address_space(3))) unsigned int*)(&wplds[it * 8192 + w * 1024]),
          16, 0, 0);
    }
  }

  // per-lane epilogue constants: e = et*32 + c, et = 0..7
  float bpe[8], wm2[8], Wl = 0.f;
  #pragma unroll
  for (int et = 0; et < 8; ++et) {
    float bv = bp[et * 32 + c];
    float wv = watt[et * 32 + c];
    bpe[et] = bv * C2LOG2E;
    wm2[et] = -2.f * wv;
    Wl += wv;
  }
  __syncthreads();

  const int gw = blockIdx.x * 8 + w;   // 0..2047

  for (int i = gw; i < 9216; i += 2048) {
    // ---- decode item -> (b, n, mt)  (validated R5-R14) --------------------
    int b = i / 1152;
    int r = i - b * 1152;
    int nt, cum;
    if      (r < 256)  { nt = 0; cum = 0; }
    else if (r < 480)  { nt = 1; cum = 256; }
    else if (r < 672)  { nt = 2; cum = 480; }
    else if (r < 832)  { nt = 3; cum = 672; }
    else if (r < 960)  { nt = 4; cum = 832; }
    else if (r < 1056) { nt = 5; cum = 960; }
    else               { nt = (r < 1120) ? 6 : 7; cum = (r < 1120) ? 1056 : 1120; }
    int rr = r - cum;
    int w8 = 8 - nt;                                       // divisor, 1..8
    int q0 = (int)(((unsigned)rr * kMagicDiv[w8]) >> 16);  // rr / w8
    int n  = nt * 32 + q0;
    int mt = nt + (rr - q0 * w8);                          // in [nt, 8)
    const int m0 = mt * 32;

    const unsigned char* xfb = (const unsigned char*)xfrag + (size_t)b * 131072;
    const unsigned char* xnbase = xfb + (nt << 14) + hi * 512 + q0 * 16;
    const unsigned char* xmbase = xfb + (mt << 14) + l * 16;

    // ---- build pp[16]: A-frags (x_n ∘ x_m), once per item (64 V regs) -----
    short8 pp[16];
    #pragma unroll
    for (int ks = 0; ks < 16; ++ks) {
      uint4 xnp = *(const uint4*)(xnbase + (ks << 10));
      uint4 xm  = *(const uint4*)(xmbase + (ks << 10));
      union U { uint4 u; short8 s; __hip_bfloat162 hh[4]; } a, mm, nn;
      mm.u = xm; nn.u = xnp;
      #pragma unroll
      for (int d = 0; d < 4; ++d) a.hh[d] = __hmul2(mm.hh[d], nn.hh[d]);
      pp[ks] = a.s;
    }

    // ---- per-et: 16-MFMA chain -> immediate tanh fold into p[16] ----------
    float p[16];
    #pragma unroll
    for (int q = 0; q < 16; ++q) p[q] = Wl;

    #pragma unroll
    for (int et = 0; et < 8; ++et) {
      f32x16 acc;
      #pragma unroll
      for (int q = 0; q < 16; ++q) acc[q] = 0.f;
      #pragma unroll
      for (int ks = 0; ks < 16; ++ks) {
        short8 bf = *(const short8*)(&wplds[((et * 16 + ks) << 10) + l * 16]);
        acc = __builtin_amdgcn_mfma_f32_32x32x16_bf16(pp[ks], bf, acc, 0, 0, 0);
      }
      const float bpet = bpe[et], wmet = wm2[et];
      #pragma unroll
      for (int q = 0; q < 16; ++q) {
        float v = fmaf(acc[q], C2LOG2E, bpet);
        p[q] = fmaf(wmet, __builtin_amdgcn_rcpf(1.f + exp2f(v)), p[q]);
      }
    }

    // ---- reduce over 32 e-cols: 4 DPP stages + 1 shfl ---------------------
    #pragma unroll
    for (int q = 0; q < 16; ++q) {
      float v = p[q];
      v = dpp_add<DPP_XOR1>(v);
      v = dpp_add<DPP_XOR2>(v);
      v = dpp_add<DPP_XOR4>(v);
      v = dpp_add<DPP_XOR8>(v);
      v += __shfl_xor(v, 16);
      p[q] = v;
    }
    if (c == 0) {
      float* outrow = sp + (size_t)(b * 256 + n) * 256 + m0;
      #pragma unroll
      for (int q = 0; q < 16; ++q) {
        int mr = (q & 3) + 8 * (q >> 2) + 4 * hi;
        outrow[mr] = p[q];
      }
      if (mt > nt) {
        #pragma unroll
        for (int q = 0; q < 16; ++q) {
          int mr = (q & 3) + 8 * (q >> 2) + 4 * hi;
          sp[(size_t)(b * 256 + m0 + mr) * 256 + n] = p[q];
        }
      }
    }
  }
}

// -------------------------------------------------------------- softmax -----
// softmax over n (axis=1) in-place on sp.  32-wide m-tiles, grid 64.
__global__ __launch_bounds__(256) void k_softmax(float* __restrict__ sp) {
  __shared__ float tile[256][33];
  __shared__ float red[8][32];
  const int t = threadIdx.x;
  const int bb = blockIdx.x >> 3, mt = blockIdx.x & 7;
  const int m0 = mt * 32;
  const int col = t & 31, g = t >> 5;   // g in [0,8)

  for (int cc = 0; cc < 32; ++cc) {
    int nn = cc * 8 + g;
    tile[nn][col] = sp[(size_t)(bb * 256 + nn) * 256 + m0 + col];
  }
  __syncthreads();
  float mx = -1e30f;
  for (int k2 = 0; k2 < 32; ++k2) mx = fmaxf(mx, tile[g * 32 + k2][col]);
  red[g][col] = mx;
  __syncthreads();
  float M = red[0][col];
  #pragma unroll
  for (int j = 1; j < 8; ++j) M = fmaxf(M, red[j][col]);
  float sm = 0.f;
  for (int k2 = 0; k2 < 32; ++k2) {
    float ev = __expf(tile[g * 32 + k2][col] - M);
    tile[g * 32 + k2][col] = ev;
    sm += ev;
  }
  __syncthreads();
  red[g][col] = sm;
  __syncthreads();
  float S = red[0][col];
  #pragma unroll
  for (int j = 1; j < 8; ++j) S += red[j][col];
  float inv = 1.0f / S;
  for (int k2 = 0; k2 < 32; ++k2) tile[g * 32 + k2][col] *= inv;
  __syncthreads();
  for (int cc = 0; cc < 32; ++cc) {
    int nn = cc * 8 + g;
    sp[(size_t)(bb * 256 + nn) * 256 + m0 + col] = tile[nn][col];
  }
}

// -------------------------------------------------------------- aggproj -----
__global__ __launch_bounds__(256) void k_aggproj(
    const float* __restrict__ x, const float* __restrict__ att,
    const float* __restrict__ W1, const float* __restrict__ b1,
    const float* __restrict__ W2, const float* __restrict__ b2,
    float* __restrict__ out, float* __restrict__ bnpart) {
  __shared__ float att8[8][256];
  __shared__ float xn8[8][256];
  __shared__ float agg8[8][256];
  const int t = threadIdx.x;
  const int bb = blockIdx.x >> 5, ng = blockIdx.x & 31;
  const int n0 = ng * 8;

  #pragma unroll
  for (int i = 0; i < 8; ++i) {
    att8[i][t] = att[(size_t)(bb * 256 + n0 + i) * 256 + t];
    xn8[i][t]  = x  [(size_t)(bb * 256 + n0 + i) * 256 + t];
  }
  __syncthreads();

  float ar[8] = {0.f, 0.f, 0.f, 0.f, 0.f, 0.f, 0.f, 0.f};
  for (int m4 = 0; m4 < 64; ++m4) {
    int m = m4 * 4;
    float xv0 = x[(size_t)(bb * 256 + m + 0) * 256 + t];
    float xv1 = x[(size_t)(bb * 256 + m + 1) * 256 + t];
    float xv2 = x[(size_t)(bb * 256 + m + 2) * 256 + t];
    float xv3 = x[(size_t)(bb * 256 + m + 3) * 256 + t];
    #pragma unroll
    for (int i = 0; i < 8; ++i) {
      float4 av = *(const float4*)&att8[i][m];
      ar[i] += av.x * xv0 + av.y * xv1 + av.z * xv2 + av.w * xv3;
    }
  }
  #pragma unroll
  for (int i = 0; i < 8; ++i) agg8[i][t] = ar[i];
  __syncthreads();

  float o[8];
  float bsum = b1[t] + b2[t];
  #pragma unroll
  for (int i = 0; i < 8; ++i) o[i] = bsum;
  for (int d4 = 0; d4 < 64; ++d4) {
    int d = d4 * 4;
    float w10 = W1[(d + 0) * 256 + t], w11 = W1[(d + 1) * 256 + t];
    float w12 = W1[(d + 2) * 256 + t], w13 = W1[(d + 3) * 256 + t];
    float w20 = W2[(d + 0) * 256 + t], w21 = W2[(d + 1) * 256 + t];
    float w22 = W2[(d + 2) * 256 + t], w23 = W2[(d + 3) * 256 + t];
    #pragma unroll
    for (int i = 0; i < 8; ++i) {
      float4 ag = *(const float4*)&agg8[i][d];
      float4 xn = *(const float4*)&xn8[i][d];
      o[i] += ag.x * w10 + ag.y * w11 + ag.z * w12 + ag.w * w13
            + xn.x * w20 + xn.y * w21 + xn.z * w22 + xn.w * w23;
    }
  }
  float s1 = 0.f, s2 = 0.f;
  #pragma unroll
  for (int i = 0; i < 8; ++i) {
    out[(size_t)(bb * 256 + n0 + i) * 256 + t] = o[i];
    s1 += o[i];
    s2 += o[i] * o[i];
  }
  bnpart[(size_t)blockIdx.x * 512 + t]       = s1;
  bnpart[(size_t)blockIdx.x * 512 + 256 + t] = s2;
}

// -------------------------------------------------------------- bnstats -----
__global__ __launch_bounds__(256) void k_bnstats(const float* __restrict__ bnpart,
                                                 float* __restrict__ bnacc) {
  __shared__ float r4[4];
  const int s = blockIdx.x;   // 0..511
  const int t = threadIdx.x;
  float v = bnpart[(size_t)t * 512 + s];
  v += __shfl_xor(v, 1);
  v += __shfl_xor(v, 2);
  v += __shfl_xor(v, 4);
  v += __shfl_xor(v, 8);
  v += __shfl_xor(v, 16);
  v += __shfl_xor(v, 32);
  if ((t & 63) == 0) r4[t >> 6] = v;
  __syncthreads();
  if (t == 0) bnacc[s] = r4[0] + r4[1] + r4[2] + r4[3];
}

// -------------------------------------------------------------- bnapply -----
__global__ __launch_bounds__(256) void k_bnapply(float* __restrict__ io,
                                                 const float* __restrict__ bnacc,
                                                 const float* __restrict__ gamma,
                                                 const float* __restrict__ beta) {
  const int e = threadIdx.x;
  float mean = bnacc[e] * (1.0f / 2048.0f);
  float var  = bnacc[256 + e] * (1.0f / 2048.0f) - mean * mean;
  float scl  = rsqrtf(var + 1e-5f) * gamma[e];
  float sh   = beta[e] - mean * scl;
  for (int r = blockIdx.x; r < 2048; r += gridDim.x) {
    float v = io[(size_t)r * 256 + e];
    float y = v * scl + sh;
    float s = (y > 0.f) ? 1.0507009873554805f * y
                        : 1.7580993408473766f * (__expf(y) - 1.0f);
    io[(size_t)r * 256 + e] = s;
  }
}

// ---------------------------------------------------------------------------
extern "C" void kernel_launch(void* const* d_in, const int* in_sizes, int n_in,
                              void* d_out, int out_size, void* d_ws, size_t ws_size,
                              hipStream_t stream) {
  const float* x     = (const float*)d_in[0];
  const float* Wp    = (const float*)d_in[1];
  const float* bp    = (const float*)d_in[2];
  const float* watt  = (const float*)d_in[3];
  const float* W1    = (const float*)d_in[4];
  const float* b1    = (const float*)d_in[5];
  const float* W2    = (const float*)d_in[6];
  const float* b2    = (const float*)d_in[7];
  const float* gamma = (const float*)d_in[8];
  const float* beta  = (const float*)d_in[9];
  float* out = (float*)d_out;
  float* ws  = (float*)d_ws;

  float* sp = ws;                                       // 524288 f32 scores/att
  unsigned int* wpfragG = (unsigned int*)(ws + 524288); // 32768 dwords (128 KB)
  unsigned int* xfragG  = wpfragG + 32768;              // 262144 dwords (1 MB)
  float* bnpart = (float*)(xfragG + 262144);            // 131072 f32
  float* bnacc  = bnpart + 131072;                      // 512 f32

  k_prep   <<<1152, 256, 0, stream>>>(x, Wp, xfragG, wpfragG);
  k_scores <<<256,  512, 0, stream>>>(xfragG, wpfragG, bp, watt, sp);
  k_softmax<<<64,   256, 0, stream>>>(sp);
  k_aggproj<<<256,  256, 0, stream>>>(x, sp, W1, b1, W2, b2, out, bnpart);
  k_bnstats<<<512,  256, 0, stream>>>(bnpart, bnacc);
  k_bnapply<<<256,  256, 0, stream>>>(out, bnacc, gamma, beta);
}

// Round 16
// 131.076 us; speedup vs baseline: 3.5869x; 3.5869x over previous
//
#include <hip/hip_runtime.h>
#include <hip/hip_bf16.h>
#include <stdint.h>

using f32x16 = __attribute__((ext_vector_type(16))) float;
using short8 = __attribute__((ext_vector_type(8))) short;

#define C2LOG2E 2.8853900817779268f   // 2*log2(e)

static __device__ __forceinline__ unsigned cvt_pk_bf16(float lo, float hi) {
  unsigned r;
  asm("v_cvt_pk_bf16_f32 %0, %1, %2" : "=v"(r) : "v"(lo), "v"(hi));
  return r;
}

// butterfly add stage via DPP (VALU, no DS); ctrl is a template constant.
template <int CTRL>
static __device__ __forceinline__ float dpp_add(float v) {
  int x = __builtin_amdgcn_update_dpp(0, __float_as_int(v), CTRL, 0xF, 0xF, true);
  return v + __int_as_float(x);
}
#define DPP_XOR1 0xB1   // quad_perm [1,0,3,2]
#define DPP_XOR2 0x4E   // quad_perm [2,3,0,1]
#define DPP_XOR4 0x141  // row_half_mirror
#define DPP_XOR8 0x140  // row_mirror

// magic multipliers indexed by DIVISOR d (1..8): q = (rr * M[d]) >> 16, exact for rr<2^10
__device__ static const unsigned kMagicDiv[9] = {0u, 65536u, 32768u, 21846u, 16384u,
                                                 13108u, 10923u, 9363u, 8192u};

// ---------------------------------------------------------------- prep ------
// Pack x and Wp into 32x32x16-MFMA fragment-linear bf16 layouts.
// 1KB block = [32 rows x 16 k] bf16: byte(rc,kk) = ((kk>>3)*32 + rc)*16 + (kk&7)*2
// xfrag : per b: blocks (mt 0..7, ks 0..15) of x[b][mt*32+row][ks*16+kk]
// wpfrag: blocks (et 0..7, ks 0..15) of Wp[ks*16+kk][et*32+col]
__global__ __launch_bounds__(256) void k_prep(const float* __restrict__ x,
                                              const float* __restrict__ Wp,
                                              unsigned int* __restrict__ xfrag,
                                              unsigned int* __restrict__ wpfrag) {
  const int bid = blockIdx.x, t = threadIdx.x;
  const int half = t >> 7, dpair = (t >> 5) & 3, rc = t & 31;
  const int kk = half * 8 + dpair * 2;
  if (bid < 1024) {
    const int b = bid >> 7, mt = (bid >> 4) & 7, ks = bid & 15;
    const int m = mt * 32 + rc;
    const int k = ks * 16 + kk;
    float2 v = *(const float2*)(x + (size_t)(b * 256 + m) * 256 + k);
    xfrag[(size_t)b * 32768 + ((mt * 16 + ks) << 8) + half * 128 + rc * 4 + dpair] =
        cvt_pk_bf16(v.x, v.y);
  } else {
    const int b2 = bid - 1024;                 // 0..127
    const int et = b2 >> 4, ks = b2 & 15;
    const int e = et * 32 + rc;
    const int k = ks * 16 + kk;
    float v0 = Wp[(size_t)k * 256 + e];
    float v1 = Wp[(size_t)(k + 1) * 256 + e];
    wpfrag[((et * 16 + ks) << 8) + half * 128 + rc * 4 + dpair] = cvt_pk_bf16(v0, v1);
  }
}

// --------------------------------------------------------------- scores -----
// Pair-items x e-half classes: item = (b, nt, q0, mt) covers rows n1=nt*32+q0
// AND n2=n1+16 vs m-tile mt (mt>=nt), for one e-half h.  4608 pairs x 2
// classes.  Per ks: 1 xm + 2 xn loads + 4 ds_reads feed 8 MFMAs -> DS per
// score HALVED vs R14 (serial-sum model: DS was the largest pipe term).
// R11's register bug fixed: unroll 2 (not 4) and NO acc->VGPR copies in the
// epilogue (fold directly from named acc) -> V~110 + A128 = ~240 -> 2
// waves/SIMD (same as R14) instead of R11's 280 -> 1 wave/SIMD.
__global__ __launch_bounds__(512, 2) void k_scores(
    const unsigned int* __restrict__ xfrag, const unsigned int* __restrict__ wpfrag,
    const float* __restrict__ bp, const float* __restrict__ watt,
    float* __restrict__ sp) {
  __shared__ unsigned char wplds[65536];

  const int tid = threadIdx.x;
  const int l = tid & 63, w = tid >> 6;          // w in [0,8)
  const int c = l & 31, hi = l >> 5;
  const int h = blockIdx.x & 1;

  // stage the e-half of Wp frag (64 KB) linearly, zero VALU
  {
    const unsigned char* src = (const unsigned char*)wpfrag + (size_t)h * 65536;
    #pragma unroll
    for (int it = 0; it < 8; ++it) {
      __builtin_amdgcn_global_load_lds(
          (const __attribute__((address_space(1))) unsigned int*)(src + it * 8192 + w * 1024 + l * 16),
          (__attribute__((address_space(3))) unsigned int*)(&wplds[it * 8192 + w * 1024]),
          16, 0, 0);
    }
  }

  // per-lane epilogue constants for this half: e = h*128 + et*32 + c
  float bpe[4], wm2[4], Wl = 0.f;
  #pragma unroll
  for (int et = 0; et < 4; ++et) {
    float bv = bp[h * 128 + et * 32 + c];
    float wv = watt[h * 128 + et * 32 + c];
    bpe[et] = bv * C2LOG2E;
    wm2[et] = -2.f * wv;
    Wl += wv;
  }
  __syncthreads();

  const int gw = (blockIdx.x >> 1) * 8 + w;   // 0..1023 within this h-class

  for (int i = gw; i < 4608; i += 1024) {
    // ---- decode pair-item -> (b, nt, q0, mt)  (validated R11) -------------
    int b = (int)((((unsigned)i >> 6) * 7282u) >> 16);     // i / 576
    int r = i - b * 576;
    int nt, cum;
    if      (r < 128) { nt = 0; cum = 0; }
    else if (r < 240) { nt = 1; cum = 128; }
    else if (r < 336) { nt = 2; cum = 240; }
    else if (r < 416) { nt = 3; cum = 336; }
    else if (r < 480) { nt = 4; cum = 416; }
    else if (r < 528) { nt = 5; cum = 480; }
    else              { nt = (r < 560) ? 6 : 7; cum = (r < 560) ? 528 : 560; }
    int rr = r - cum;
    int d8 = 8 - nt;                                       // divisor, 1..8
    int q0 = (int)(((unsigned)rr * kMagicDiv[d8]) >> 16);  // rr / d8, q0 in [0,16)
    int mt = nt + (rr - q0 * d8);                          // in [nt, 8)
    const int n1 = nt * 32 + q0, n2 = n1 + 16;
    const int m0 = mt * 32;

    const unsigned char* xfb = (const unsigned char*)xfrag + (size_t)b * 131072;
    const unsigned char* xmb = xfb + (mt << 14) + l * 16;
    const unsigned char* xnb = xfb + (nt << 14) + hi * 512 + q0 * 16;

    // ---- acc[2n][4et] = 128 AGPR ------------------------------------------
    f32x16 a10, a11, a12, a13, a20, a21, a22, a23;
    #pragma unroll
    for (int q = 0; q < 16; ++q) {
      a10[q] = 0.f; a11[q] = 0.f; a12[q] = 0.f; a13[q] = 0.f;
      a20[q] = 0.f; a21[q] = 0.f; a22[q] = 0.f; a23[q] = 0.f;
    }

    #pragma unroll 2
    for (int ks = 0; ks < 16; ++ks) {
      uint4 xm = *(const uint4*)(xmb + (ks << 10));
      uint4 x1 = *(const uint4*)(xnb + (ks << 10));
      uint4 x2 = *(const uint4*)(xnb + (ks << 10) + 256);   // row q0+16
      union U { uint4 u; short8 s; __hip_bfloat162 hh[4]; } m, u1, u2, p1, p2;
      m.u = xm; u1.u = x1; u2.u = x2;
      #pragma unroll
      for (int dd = 0; dd < 4; ++dd) {
        p1.hh[dd] = __hmul2(m.hh[dd], u1.hh[dd]);
        p2.hh[dd] = __hmul2(m.hh[dd], u2.hh[dd]);
      }
      short8 b0 = *(const short8*)(&wplds[((0 * 16 + ks) << 10) + l * 16]);
      short8 b1 = *(const short8*)(&wplds[((1 * 16 + ks) << 10) + l * 16]);
      short8 b2 = *(const short8*)(&wplds[((2 * 16 + ks) << 10) + l * 16]);
      short8 b3 = *(const short8*)(&wplds[((3 * 16 + ks) << 10) + l * 16]);
      a10 = __builtin_amdgcn_mfma_f32_32x32x16_bf16(p1.s, b0, a10, 0, 0, 0);
      a11 = __builtin_amdgcn_mfma_f32_32x32x16_bf16(p1.s, b1, a11, 0, 0, 0);
      a12 = __builtin_amdgcn_mfma_f32_32x32x16_bf16(p1.s, b2, a12, 0, 0, 0);
      a13 = __builtin_amdgcn_mfma_f32_32x32x16_bf16(p1.s, b3, a13, 0, 0, 0);
      a20 = __builtin_amdgcn_mfma_f32_32x32x16_bf16(p2.s, b0, a20, 0, 0, 0);
      a21 = __builtin_amdgcn_mfma_f32_32x32x16_bf16(p2.s, b1, a21, 0, 0, 0);
      a22 = __builtin_amdgcn_mfma_f32_32x32x16_bf16(p2.s, b2, a22, 0, 0, 0);
      a23 = __builtin_amdgcn_mfma_f32_32x32x16_bf16(p2.s, b3, a23, 0, 0, 0);
    }

    float* base = sp + (size_t)h * 524288;

    // ---- n1: fold directly from a10..a13 (NO acc copies), reduce, write ---
    {
      float p[16];
      #pragma unroll
      for (int q = 0; q < 16; ++q) {
        float v0 = fmaf(a10[q], C2LOG2E, bpe[0]);
        float pq = fmaf(wm2[0], __builtin_amdgcn_rcpf(1.f + exp2f(v0)), Wl);
        float v1 = fmaf(a11[q], C2LOG2E, bpe[1]);
        pq = fmaf(wm2[1], __builtin_amdgcn_rcpf(1.f + exp2f(v1)), pq);
        float v2 = fmaf(a12[q], C2LOG2E, bpe[2]);
        pq = fmaf(wm2[2], __builtin_amdgcn_rcpf(1.f + exp2f(v2)), pq);
        float v3 = fmaf(a13[q], C2LOG2E, bpe[3]);
        pq = fmaf(wm2[3], __builtin_amdgcn_rcpf(1.f + exp2f(v3)), pq);
        p[q] = pq;
      }
      #pragma unroll
      for (int q = 0; q < 16; ++q) {
        float v = p[q];
        v = dpp_add<DPP_XOR1>(v);
        v = dpp_add<DPP_XOR2>(v);
        v = dpp_add<DPP_XOR4>(v);
        v = dpp_add<DPP_XOR8>(v);
        v += __shfl_xor(v, 16);
        p[q] = v;
      }
      if (c == 0) {
        float* outrow = base + (size_t)(b * 256 + n1) * 256 + m0;
        #pragma unroll
        for (int q = 0; q < 16; ++q) {
          int mr = (q & 3) + 8 * (q >> 2) + 4 * hi;
          outrow[mr] = p[q];
        }
        if (mt > nt) {
          #pragma unroll
          for (int q = 0; q < 16; ++q) {
            int mr = (q & 3) + 8 * (q >> 2) + 4 * hi;
            base[(size_t)(b * 256 + m0 + mr) * 256 + n1] = p[q];
          }
        }
      }
    }

    // ---- n2: fold directly from a20..a23, reduce, write -------------------
    {
      float p[16];
      #pragma unroll
      for (int q = 0; q < 16; ++q) {
        float v0 = fmaf(a20[q], C2LOG2E, bpe[0]);
        float pq = fmaf(wm2[0], __builtin_amdgcn_rcpf(1.f + exp2f(v0)), Wl);
        float v1 = fmaf(a21[q], C2LOG2E, bpe[1]);
        pq = fmaf(wm2[1], __builtin_amdgcn_rcpf(1.f + exp2f(v1)), pq);
        float v2 = fmaf(a22[q], C2LOG2E, bpe[2]);
        pq = fmaf(wm2[2], __builtin_amdgcn_rcpf(1.f + exp2f(v2)), pq);
        float v3 = fmaf(a23[q], C2LOG2E, bpe[3]);
        pq = fmaf(wm2[3], __builtin_amdgcn_rcpf(1.f + exp2f(v3)), pq);
        p[q] = pq;
      }
      #pragma unroll
      for (int q = 0; q < 16; ++q) {
        float v = p[q];
        v = dpp_add<DPP_XOR1>(v);
        v = dpp_add<DPP_XOR2>(v);
        v = dpp_add<DPP_XOR4>(v);
        v = dpp_add<DPP_XOR8>(v);
        v += __shfl_xor(v, 16);
        p[q] = v;
      }
      if (c == 0) {
        float* outrow = base + (size_t)(b * 256 + n2) * 256 + m0;
        #pragma unroll
        for (int q = 0; q < 16; ++q) {
          int mr = (q & 3) + 8 * (q >> 2) + 4 * hi;
          outrow[mr] = p[q];
        }
        if (mt > nt) {
          #pragma unroll
          for (int q = 0; q < 16; ++q) {
            int mr = (q & 3) + 8 * (q >> 2) + 4 * hi;
            base[(size_t)(b * 256 + m0 + mr) * 256 + n2] = p[q];
          }
        }
      }
    }
  }
}

// -------------------------------------------------------------- softmax -----
// sum the two e-half partials, softmax over n (axis=1), write att into sp[0].
__global__ __launch_bounds__(256) void k_softmax(float* __restrict__ sp) {
  __shared__ float tile[256][65];
  __shared__ float red[4][64];
  const int t = threadIdx.x;
  const int bb = blockIdx.x >> 2, mt = blockIdx.x & 3;
  const int m0 = mt * 64;

  for (int c = 0; c < 64; ++c) {
    int nn = c * 4 + (t >> 6);
    size_t idx = (size_t)(bb * 256 + nn) * 256 + m0 + (t & 63);
    tile[nn][t & 63] = sp[idx] + sp[524288 + idx];
  }
  __syncthreads();
  const int col = t & 63, g = t >> 6;
  float mx = -1e30f;
  for (int k2 = 0; k2 < 64; ++k2) mx = fmaxf(mx, tile[g * 64 + k2][col]);
  red[g][col] = mx;
  __syncthreads();
  float M = fmaxf(fmaxf(red[0][col], red[1][col]), fmaxf(red[2][col], red[3][col]));
  float sm = 0.f;
  for (int k2 = 0; k2 < 64; ++k2) {
    float ev = __expf(tile[g * 64 + k2][col] - M);
    tile[g * 64 + k2][col] = ev;
    sm += ev;
  }
  __syncthreads();
  red[g][col] = sm;
  __syncthreads();
  float inv = 1.0f / (red[0][col] + red[1][col] + red[2][col] + red[3][col]);
  for (int k2 = 0; k2 < 64; ++k2) tile[g * 64 + k2][col] *= inv;
  __syncthreads();
  for (int c = 0; c < 64; ++c) {
    int nn = c * 4 + (t >> 6);
    sp[(size_t)(bb * 256 + nn) * 256 + m0 + (t & 63)] = tile[nn][t & 63];
  }
}

// -------------------------------------------------------------- aggproj -----
__global__ __launch_bounds__(256) void k_aggproj(
    const float* __restrict__ x, const float* __restrict__ att,
    const float* __restrict__ W1, const float* __restrict__ b1,
    const float* __restrict__ W2, const float* __restrict__ b2,
    float* __restrict__ out, float* __restrict__ bnpart) {
  __shared__ float att8[8][256];
  __shared__ float xn8[8][256];
  __shared__ float agg8[8][256];
  const int t = threadIdx.x;
  const int bb = blockIdx.x >> 5, ng = blockIdx.x & 31;
  const int n0 = ng * 8;

  #pragma unroll
  for (int i = 0; i < 8; ++i) {
    att8[i][t] = att[(size_t)(bb * 256 + n0 + i) * 256 + t];
    xn8[i][t]  = x  [(size_t)(bb * 256 + n0 + i) * 256 + t];
  }
  __syncthreads();

  float ar[8] = {0.f, 0.f, 0.f, 0.f, 0.f, 0.f, 0.f, 0.f};
  for (int m4 = 0; m4 < 64; ++m4) {
    int m = m4 * 4;
    float xv0 = x[(size_t)(bb * 256 + m + 0) * 256 + t];
    float xv1 = x[(size_t)(bb * 256 + m + 1) * 256 + t];
    float xv2 = x[(size_t)(bb * 256 + m + 2) * 256 + t];
    float xv3 = x[(size_t)(bb * 256 + m + 3) * 256 + t];
    #pragma unroll
    for (int i = 0; i < 8; ++i) {
      float4 av = *(const float4*)&att8[i][m];
      ar[i] += av.x * xv0 + av.y * xv1 + av.z * xv2 + av.w * xv3;
    }
  }
  #pragma unroll
  for (int i = 0; i < 8; ++i) agg8[i][t] = ar[i];
  __syncthreads();

  float o[8];
  float bsum = b1[t] + b2[t];
  #pragma unroll
  for (int i = 0; i < 8; ++i) o[i] = bsum;
  for (int d4 = 0; d4 < 64; ++d4) {
    int d = d4 * 4;
    float w10 = W1[(d + 0) * 256 + t], w11 = W1[(d + 1) * 256 + t];
    float w12 = W1[(d + 2) * 256 + t], w13 = W1[(d + 3) * 256 + t];
    float w20 = W2[(d + 0) * 256 + t], w21 = W2[(d + 1) * 256 + t];
    float w22 = W2[(d + 2) * 256 + t], w23 = W2[(d + 3) * 256 + t];
    #pragma unroll
    for (int i = 0; i < 8; ++i) {
      float4 ag = *(const float4*)&agg8[i][d];
      float4 xn = *(const float4*)&xn8[i][d];
      o[i] += ag.x * w10 + ag.y * w11 + ag.z * w12 + ag.w * w13
            + xn.x * w20 + xn.y * w21 + xn.z * w22 + xn.w * w23;
    }
  }
  float s1 = 0.f, s2 = 0.f;
  #pragma unroll
  for (int i = 0; i < 8; ++i) {
    out[(size_t)(bb * 256 + n0 + i) * 256 + t] = o[i];
    s1 += o[i];
    s2 += o[i] * o[i];
  }
  bnpart[(size_t)blockIdx.x * 512 + t]       = s1;
  bnpart[(size_t)blockIdx.x * 512 + 256 + t] = s2;
}

// -------------------------------------------------------------- bnstats -----
__global__ __launch_bounds__(256) void k_bnstats(const float* __restrict__ bnpart,
                                                 float* __restrict__ bnacc) {
  __shared__ float r4[4];
  const int s = blockIdx.x;   // 0..511
  const int t = threadIdx.x;
  float v = bnpart[(size_t)t * 512 + s];
  v += __shfl_xor(v, 1);
  v += __shfl_xor(v, 2);
  v += __shfl_xor(v, 4);
  v += __shfl_xor(v, 8);
  v += __shfl_xor(v, 16);
  v += __shfl_xor(v, 32);
  if ((t & 63) == 0) r4[t >> 6] = v;
  __syncthreads();
  if (t == 0) bnacc[s] = r4[0] + r4[1] + r4[2] + r4[3];
}

// -------------------------------------------------------------- bnapply -----
__global__ __launch_bounds__(256) void k_bnapply(float* __restrict__ io,
                                                 const float* __restrict__ bnacc,
                                                 const float* __restrict__ gamma,
                                                 const float* __restrict__ beta) {
  const int e = threadIdx.x;
  float mean = bnacc[e] * (1.0f / 2048.0f);
  float var  = bnacc[256 + e] * (1.0f / 2048.0f) - mean * mean;
  float scl  = rsqrtf(var + 1e-5f) * gamma[e];
  float sh   = beta[e] - mean * scl;
  for (int r = blockIdx.x; r < 2048; r += gridDim.x) {
    float v = io[(size_t)r * 256 + e];
    float y = v * scl + sh;
    float s = (y > 0.f) ? 1.0507009873554805f * y
                        : 1.7580993408473766f * (__expf(y) - 1.0f);
    io[(size_t)r * 256 + e] = s;
  }
}

// ---------------------------------------------------------------------------
extern "C" void kernel_launch(void* const* d_in, const int* in_sizes, int n_in,
                              void* d_out, int out_size, void* d_ws, size_t ws_size,
                              hipStream_t stream) {
  const float* x     = (const float*)d_in[0];
  const float* Wp    = (const float*)d_in[1];
  const float* bp    = (const float*)d_in[2];
  const float* watt  = (const float*)d_in[3];
  const float* W1    = (const float*)d_in[4];
  const float* b1    = (const float*)d_in[5];
  const float* W2    = (const float*)d_in[6];
  const float* b2    = (const float*)d_in[7];
  const float* gamma = (const float*)d_in[8];
  const float* beta  = (const float*)d_in[9];
  float* out = (float*)d_out;
  float* ws  = (float*)d_ws;

  float* sp = ws;                                        // [2][524288] f32 partials
  unsigned int* wpfragG = (unsigned int*)(ws + 1048576); // 32768 dwords (128 KB)
  unsigned int* xfragG  = wpfragG + 32768;               // 262144 dwords (1 MB)
  float* bnpart = ws + 524288;                           // aliases sp[1] (dead after softmax)
  float* bnacc  = bnpart + 131072;

  k_prep   <<<1152, 256, 0, stream>>>(x, Wp, xfragG, wpfragG);
  k_scores <<<256,  512, 0, stream>>>(xfragG, wpfragG, bp, watt, sp);
  k_softmax<<<32,   256, 0, stream>>>(sp);
  k_aggproj<<<256,  256, 0, stream>>>(x, sp, W1, b1, W2, b2, out, bnpart);
  k_bnstats<<<512,  256, 0, stream>>>(bnpart, bnacc);
  k_bnapply<<<256,  256, 0, stream>>>(out, bnacc, gamma, beta);
}

// Round 17
// 121.772 us; speedup vs baseline: 3.8609x; 1.0764x over previous
//
#include <hip/hip_runtime.h>
#include <hip/hip_bf16.h>
#include <stdint.h>

using f32x16 = __attribute__((ext_vector_type(16))) float;
using short8 = __attribute__((ext_vector_type(8))) short;

#define C2LOG2E 2.8853900817779268f   // 2*log2(e)

static __device__ __forceinline__ unsigned cvt_pk_bf16(float lo, float hi) {
  unsigned r;
  asm("v_cvt_pk_bf16_f32 %0, %1, %2" : "=v"(r) : "v"(lo), "v"(hi));
  return r;
}

// butterfly add stage via DPP (VALU, no DS); ctrl is a template constant.
template <int CTRL>
static __device__ __forceinline__ float dpp_add(float v) {
  int x = __builtin_amdgcn_update_dpp(0, __float_as_int(v), CTRL, 0xF, 0xF, true);
  return v + __int_as_float(x);
}
#define DPP_XOR1 0xB1   // quad_perm [1,0,3,2]
#define DPP_XOR2 0x4E   // quad_perm [2,3,0,1]
#define DPP_XOR4 0x141  // row_half_mirror
#define DPP_XOR8 0x140  // row_mirror

// magic multipliers indexed by DIVISOR d (1..8): q = (rr * M[d]) >> 16, exact for rr<2^10
__device__ static const unsigned kMagicDiv[9] = {0u, 65536u, 32768u, 21846u, 16384u,
                                                 13108u, 10923u, 9363u, 8192u};

// ---------------------------------------------------------------- prep ------
// Pack x and Wp into 32x32x16-MFMA fragment-linear bf16 layouts; block 0 also
// zeroes bnacc (aggproj accumulates BN stats there via atomics; prep completes
// before aggproj launches, so ordering is guaranteed).
__global__ __launch_bounds__(256) void k_prep(const float* __restrict__ x,
                                              const float* __restrict__ Wp,
                                              unsigned int* __restrict__ xfrag,
                                              unsigned int* __restrict__ wpfrag,
                                              float* __restrict__ bnacc) {
  const int bid = blockIdx.x, t = threadIdx.x;
  if (bid == 0) {
    bnacc[t] = 0.f;
    bnacc[256 + t] = 0.f;
  }
  const int half = t >> 7, dpair = (t >> 5) & 3, rc = t & 31;
  const int kk = half * 8 + dpair * 2;
  if (bid < 1024) {
    const int b = bid >> 7, mt = (bid >> 4) & 7, ks = bid & 15;
    const int m = mt * 32 + rc;
    const int k = ks * 16 + kk;
    float2 v = *(const float2*)(x + (size_t)(b * 256 + m) * 256 + k);
    xfrag[(size_t)b * 32768 + ((mt * 16 + ks) << 8) + half * 128 + rc * 4 + dpair] =
        cvt_pk_bf16(v.x, v.y);
  } else {
    const int b2 = bid - 1024;                 // 0..127
    const int et = b2 >> 4, ks = b2 & 15;
    const int e = et * 32 + rc;
    const int k = ks * 16 + kk;
    float v0 = Wp[(size_t)k * 256 + e];
    float v1 = Wp[(size_t)(k + 1) * 256 + e];
    wpfrag[((et * 16 + ks) << 8) + half * 128 + rc * 4 + dpair] = cvt_pk_bf16(v0, v1);
  }
}

// --------------------------------------------------------------- scores -----
// R14 structure (best measured: 72.5us).  Full-e items (b, n, mt), mt >= n>>5:
// 9216 total.  Block = 512 thr / 8 waves; full Wp (128 KB) in LDS -> 1
// block/CU.  acc = 8 x f32x16 (128 A) + transient per-ks A-build (V~116) ->
// 2 waves/SIMD, no spill.  Known plateau ~72us: insensitive to DS volume
// (R16), TLP (R13), item granularity (R8/R10) — distributed dep-stall.
__global__ __launch_bounds__(512, 2) void k_scores(
    const unsigned int* __restrict__ xfrag, const unsigned int* __restrict__ wpfrag,
    const float* __restrict__ bp, const float* __restrict__ watt,
    float* __restrict__ sp) {
  __shared__ unsigned char wplds[131072];

  const int tid = threadIdx.x;
  const int l = tid & 63, w = tid >> 6;          // w in [0,8)
  const int c = l & 31, hi = l >> 5;

  // stage full Wp frag (128 KB) linearly, zero VALU (8 waves x 16 it x 1KB)
  {
    const unsigned char* src = (const unsigned char*)wpfrag;
    #pragma unroll
    for (int it = 0; it < 16; ++it) {
      __builtin_amdgcn_global_load_lds(
          (const __attribute__((address_space(1))) unsigned int*)(src + it * 8192 + w * 1024 + l * 16),
          (__attribute__((address_space(3))) unsigned int*)(&wplds[it * 8192 + w * 1024]),
          16, 0, 0);
    }
  }

  // per-lane epilogue constants: e = et*32 + c, et = 0..7
  float bpe[8], wm2[8], Wl = 0.f;
  #pragma unroll
  for (int et = 0; et < 8; ++et) {
    float bv = bp[et * 32 + c];
    float wv = watt[et * 32 + c];
    bpe[et] = bv * C2LOG2E;
    wm2[et] = -2.f * wv;
    Wl += wv;
  }
  __syncthreads();

  const int gw = blockIdx.x * 8 + w;   // 0..2047

  for (int i = gw; i < 9216; i += 2048) {
    // ---- decode item -> (b, n, mt)  (validated R5-R16) --------------------
    int b = i / 1152;
    int r = i - b * 1152;
    int nt, cum;
    if      (r < 256)  { nt = 0; cum = 0; }
    else if (r < 480)  { nt = 1; cum = 256; }
    else if (r < 672)  { nt = 2; cum = 480; }
    else if (r < 832)  { nt = 3; cum = 672; }
    else if (r < 960)  { nt = 4; cum = 832; }
    else if (r < 1056) { nt = 5; cum = 960; }
    else               { nt = (r < 1120) ? 6 : 7; cum = (r < 1120) ? 1056 : 1120; }
    int rr = r - cum;
    int w8 = 8 - nt;                                       // divisor, 1..8
    int q0 = (int)(((unsigned)rr * kMagicDiv[w8]) >> 16);  // rr / w8
    int n  = nt * 32 + q0;
    int mt = nt + (rr - q0 * w8);                          // in [nt, 8)
    const int m0 = mt * 32;

    const unsigned char* xfb = (const unsigned char*)xfrag + (size_t)b * 131072;
    const unsigned char* xnbase = xfb + (nt << 14) + hi * 512 + q0 * 16;
    const unsigned char* xmbase = xfb + (mt << 14) + l * 16;

    // ---- full-e accumulation: acc[8] f32x16 (128 AGPR) --------------------
    f32x16 acc[8];
    #pragma unroll
    for (int et = 0; et < 8; ++et)
      #pragma unroll
      for (int q = 0; q < 16; ++q) acc[et][q] = 0.f;

    #pragma unroll 2
    for (int ks = 0; ks < 16; ++ks) {
      // transient A-frag: (x_n ∘ x_m) built per k-step, ONCE per item
      uint4 xnp = *(const uint4*)(xnbase + (ks << 10));
      uint4 xm  = *(const uint4*)(xmbase + (ks << 10));
      union U { uint4 u; short8 s; __hip_bfloat162 hh[4]; } a, mm, nn;
      mm.u = xm; nn.u = xnp;
      #pragma unroll
      for (int d = 0; d < 4; ++d) a.hh[d] = __hmul2(mm.hh[d], nn.hh[d]);

      #pragma unroll
      for (int et = 0; et < 8; ++et) {
        short8 bf = *(const short8*)(&wplds[((et * 16 + ks) << 10) + l * 16]);
        acc[et] = __builtin_amdgcn_mfma_f32_32x32x16_bf16(a.s, bf, acc[et], 0, 0, 0);
      }
    }

    // ---- epilogue: p[m] = Wl + sum_et wm2*rcp(1+exp2(acc*C + bpe)) --------
    float p[16];
    #pragma unroll
    for (int q = 0; q < 16; ++q) {
      float pq = Wl;
      #pragma unroll
      for (int et = 0; et < 8; ++et) {
        float v = fmaf(acc[et][q], C2LOG2E, bpe[et]);
        pq = fmaf(wm2[et], __builtin_amdgcn_rcpf(1.f + exp2f(v)), pq);
      }
      p[q] = pq;
    }

    // ---- reduce over 32 e-cols: 4 DPP stages + 1 shfl ---------------------
    #pragma unroll
    for (int q = 0; q < 16; ++q) {
      float v = p[q];
      v = dpp_add<DPP_XOR1>(v);
      v = dpp_add<DPP_XOR2>(v);
      v = dpp_add<DPP_XOR4>(v);
      v = dpp_add<DPP_XOR8>(v);
      v += __shfl_xor(v, 16);
      p[q] = v;
    }
    if (c == 0) {
      float* outrow = sp + (size_t)(b * 256 + n) * 256 + m0;
      #pragma unroll
      for (int q = 0; q < 16; ++q) {
        int mr = (q & 3) + 8 * (q >> 2) + 4 * hi;
        outrow[mr] = p[q];
      }
      if (mt > nt) {
        #pragma unroll
        for (int q = 0; q < 16; ++q) {
          int mr = (q & 3) + 8 * (q >> 2) + 4 * hi;
          sp[(size_t)(b * 256 + m0 + mr) * 256 + n] = p[q];
        }
      }
    }
  }
}

// -------------------------------------------------------------- softmax -----
// softmax over n (axis=1) in-place on sp.  32-wide m-tiles, grid 64.
__global__ __launch_bounds__(256) void k_softmax(float* __restrict__ sp) {
  __shared__ float tile[256][33];
  __shared__ float red[8][32];
  const int t = threadIdx.x;
  const int bb = blockIdx.x >> 3, mt = blockIdx.x & 7;
  const int m0 = mt * 32;
  const int col = t & 31, g = t >> 5;   // g in [0,8)

  for (int cc = 0; cc < 32; ++cc) {
    int nn = cc * 8 + g;
    tile[nn][col] = sp[(size_t)(bb * 256 + nn) * 256 + m0 + col];
  }
  __syncthreads();
  float mx = -1e30f;
  for (int k2 = 0; k2 < 32; ++k2) mx = fmaxf(mx, tile[g * 32 + k2][col]);
  red[g][col] = mx;
  __syncthreads();
  float M = red[0][col];
  #pragma unroll
  for (int j = 1; j < 8; ++j) M = fmaxf(M, red[j][col]);
  float sm = 0.f;
  for (int k2 = 0; k2 < 32; ++k2) {
    float ev = __expf(tile[g * 32 + k2][col] - M);
    tile[g * 32 + k2][col] = ev;
    sm += ev;
  }
  __syncthreads();
  red[g][col] = sm;
  __syncthreads();
  float S = red[0][col];
  #pragma unroll
  for (int j = 1; j < 8; ++j) S += red[j][col];
  float inv = 1.0f / S;
  for (int k2 = 0; k2 < 32; ++k2) tile[g * 32 + k2][col] *= inv;
  __syncthreads();
  for (int cc = 0; cc < 32; ++cc) {
    int nn = cc * 8 + g;
    sp[(size_t)(bb * 256 + nn) * 256 + m0 + col] = tile[nn][col];
  }
}

// -------------------------------------------------------------- aggproj -----
// out[n,e] = (att[n,:] @ x_b) @ W1 + x_n @ W2 + b1 + b2; BN partial sums go
// straight into bnacc via atomics (bnacc zeroed by k_prep; per-address adds =
// 512, spread over 512 addresses -> negligible contention).
__global__ __launch_bounds__(256) void k_aggproj(
    const float* __restrict__ x, const float* __restrict__ att,
    const float* __restrict__ W1, const float* __restrict__ b1,
    const float* __restrict__ W2, const float* __restrict__ b2,
    float* __restrict__ out, float* __restrict__ bnacc) {
  __shared__ float att8[8][256];
  __shared__ float xn8[8][256];
  __shared__ float agg8[8][256];
  const int t = threadIdx.x;
  const int bb = blockIdx.x >> 5, ng = blockIdx.x & 31;
  const int n0 = ng * 8;

  #pragma unroll
  for (int i = 0; i < 8; ++i) {
    att8[i][t] = att[(size_t)(bb * 256 + n0 + i) * 256 + t];
    xn8[i][t]  = x  [(size_t)(bb * 256 + n0 + i) * 256 + t];
  }
  __syncthreads();

  float ar[8] = {0.f, 0.f, 0.f, 0.f, 0.f, 0.f, 0.f, 0.f};
  for (int m4 = 0; m4 < 64; ++m4) {
    int m = m4 * 4;
    float xv0 = x[(size_t)(bb * 256 + m + 0) * 256 + t];
    float xv1 = x[(size_t)(bb * 256 + m + 1) * 256 + t];
    float xv2 = x[(size_t)(bb * 256 + m + 2) * 256 + t];
    float xv3 = x[(size_t)(bb * 256 + m + 3) * 256 + t];
    #pragma unroll
    for (int i = 0; i < 8; ++i) {
      float4 av = *(const float4*)&att8[i][m];
      ar[i] += av.x * xv0 + av.y * xv1 + av.z * xv2 + av.w * xv3;
    }
  }
  #pragma unroll
  for (int i = 0; i < 8; ++i) agg8[i][t] = ar[i];
  __syncthreads();

  float o[8];
  float bsum = b1[t] + b2[t];
  #pragma unroll
  for (int i = 0; i < 8; ++i) o[i] = bsum;
  for (int d4 = 0; d4 < 64; ++d4) {
    int d = d4 * 4;
    float w10 = W1[(d + 0) * 256 + t], w11 = W1[(d + 1) * 256 + t];
    float w12 = W1[(d + 2) * 256 + t], w13 = W1[(d + 3) * 256 + t];
    float w20 = W2[(d + 0) * 256 + t], w21 = W2[(d + 1) * 256 + t];
    float w22 = W2[(d + 2) * 256 + t], w23 = W2[(d + 3) * 256 + t];
    #pragma unroll
    for (int i = 0; i < 8; ++i) {
      float4 ag = *(const float4*)&agg8[i][d];
      float4 xn = *(const float4*)&xn8[i][d];
      o[i] += ag.x * w10 + ag.y * w11 + ag.z * w12 + ag.w * w13
            + xn.x * w20 + xn.y * w21 + xn.z * w22 + xn.w * w23;
    }
  }
  float s1 = 0.f, s2 = 0.f;
  #pragma unroll
  for (int i = 0; i < 8; ++i) {
    out[(size_t)(bb * 256 + n0 + i) * 256 + t] = o[i];
    s1 += o[i];
    s2 += o[i] * o[i];
  }
  atomicAdd(&bnacc[t], s1);
  atomicAdd(&bnacc[256 + t], s2);
}

// -------------------------------------------------------------- bnapply -----
__global__ __launch_bounds__(256) void k_bnapply(float* __restrict__ io,
                                                 const float* __restrict__ bnacc,
                                                 const float* __restrict__ gamma,
                                                 const float* __restrict__ beta) {
  const int e = threadIdx.x;
  float mean = bnacc[e] * (1.0f / 2048.0f);
  float var  = bnacc[256 + e] * (1.0f / 2048.0f) - mean * mean;
  float scl  = rsqrtf(var + 1e-5f) * gamma[e];
  float sh   = beta[e] - mean * scl;
  for (int r = blockIdx.x; r < 2048; r += gridDim.x) {
    float v = io[(size_t)r * 256 + e];
    float y = v * scl + sh;
    float s = (y > 0.f) ? 1.0507009873554805f * y
                        : 1.7580993408473766f * (__expf(y) - 1.0f);
    io[(size_t)r * 256 + e] = s;
  }
}

// ---------------------------------------------------------------------------
extern "C" void kernel_launch(void* const* d_in, const int* in_sizes, int n_in,
                              void* d_out, int out_size, void* d_ws, size_t ws_size,
                              hipStream_t stream) {
  const float* x     = (const float*)d_in[0];
  const float* Wp    = (const float*)d_in[1];
  const float* bp    = (const float*)d_in[2];
  const float* watt  = (const float*)d_in[3];
  const float* W1    = (const float*)d_in[4];
  const float* b1    = (const float*)d_in[5];
  const float* W2    = (const float*)d_in[6];
  const float* b2    = (const float*)d_in[7];
  const float* gamma = (const float*)d_in[8];
  const float* beta  = (const float*)d_in[9];
  float* out = (float*)d_out;
  float* ws  = (float*)d_ws;

  float* sp = ws;                                       // 524288 f32 scores/att
  unsigned int* wpfragG = (unsigned int*)(ws + 524288); // 32768 dwords (128 KB)
  unsigned int* xfragG  = wpfragG + 32768;              // 262144 dwords (1 MB)
  float* bnacc  = (float*)(xfragG + 262144);            // 512 f32

  k_prep   <<<1152, 256, 0, stream>>>(x, Wp, xfragG, wpfragG, bnacc);
  k_scores <<<256,  512, 0, stream>>>(xfragG, wpfragG, bp, watt, sp);
  k_softmax<<<64,   256, 0, stream>>>(sp);
  k_aggproj<<<256,  256, 0, stream>>>(x, sp, W1, b1, W2, b2, out, bnacc);
  k_bnapply<<<256,  256, 0, stream>>>(out, bnacc, gamma, beta);
}

// Round 18
// 120.888 us; speedup vs baseline: 3.8892x; 1.0073x over previous
//
#include <hip/hip_runtime.h>
#include <hip/hip_bf16.h>
#include <stdint.h>

using f32x16 = __attribute__((ext_vector_type(16))) float;
using short8 = __attribute__((ext_vector_type(8))) short;

#define C2LOG2E 2.8853900817779268f   // 2*log2(e)

static __device__ __forceinline__ unsigned cvt_pk_bf16(float lo, float hi) {
  unsigned r;
  asm("v_cvt_pk_bf16_f32 %0, %1, %2" : "=v"(r) : "v"(lo), "v"(hi));
  return r;
}

// butterfly add stage via DPP (VALU, no DS); ctrl is a template constant.
template <int CTRL>
static __device__ __forceinline__ float dpp_add(float v) {
  int x = __builtin_amdgcn_update_dpp(0, __float_as_int(v), CTRL, 0xF, 0xF, true);
  return v + __int_as_float(x);
}
#define DPP_XOR1 0xB1   // quad_perm [1,0,3,2]
#define DPP_XOR2 0x4E   // quad_perm [2,3,0,1]
#define DPP_XOR4 0x141  // row_half_mirror
#define DPP_XOR8 0x140  // row_mirror

// magic multipliers indexed by DIVISOR d (1..8): q = (rr * M[d]) >> 16, exact for rr<2^10
__device__ static const unsigned kMagicDiv[9] = {0u, 65536u, 32768u, 21846u, 16384u,
                                                 13108u, 10923u, 9363u, 8192u};

// ---------------------------------------------------------------- prep ------
// Pack x and Wp into 32x32x16-MFMA fragment-linear bf16 layouts; block 0 also
// zeroes bnacc (aggproj accumulates BN stats there via atomics; prep completes
// before aggproj launches, so ordering is guaranteed).
__global__ __launch_bounds__(256) void k_prep(const float* __restrict__ x,
                                              const float* __restrict__ Wp,
                                              unsigned int* __restrict__ xfrag,
                                              unsigned int* __restrict__ wpfrag,
                                              float* __restrict__ bnacc) {
  const int bid = blockIdx.x, t = threadIdx.x;
  if (bid == 0) {
    bnacc[t] = 0.f;
    bnacc[256 + t] = 0.f;
  }
  const int half = t >> 7, dpair = (t >> 5) & 3, rc = t & 31;
  const int kk = half * 8 + dpair * 2;
  if (bid < 1024) {
    const int b = bid >> 7, mt = (bid >> 4) & 7, ks = bid & 15;
    const int m = mt * 32 + rc;
    const int k = ks * 16 + kk;
    float2 v = *(const float2*)(x + (size_t)(b * 256 + m) * 256 + k);
    xfrag[(size_t)b * 32768 + ((mt * 16 + ks) << 8) + half * 128 + rc * 4 + dpair] =
        cvt_pk_bf16(v.x, v.y);
  } else {
    const int b2 = bid - 1024;                 // 0..127
    const int et = b2 >> 4, ks = b2 & 15;
    const int e = et * 32 + rc;
    const int k = ks * 16 + kk;
    float v0 = Wp[(size_t)k * 256 + e];
    float v1 = Wp[(size_t)(k + 1) * 256 + e];
    wpfrag[((et * 16 + ks) << 8) + half * 128 + rc * 4 + dpair] = cvt_pk_bf16(v0, v1);
  }
}

// --------------------------------------------------------------- scores -----
// R14 structure (best measured: 72.5us) — UNCHANGED from R17.
__global__ __launch_bounds__(512, 2) void k_scores(
    const unsigned int* __restrict__ xfrag, const unsigned int* __restrict__ wpfrag,
    const float* __restrict__ bp, const float* __restrict__ watt,
    float* __restrict__ sp) {
  __shared__ unsigned char wplds[131072];

  const int tid = threadIdx.x;
  const int l = tid & 63, w = tid >> 6;          // w in [0,8)
  const int c = l & 31, hi = l >> 5;

  // stage full Wp frag (128 KB) linearly, zero VALU (8 waves x 16 it x 1KB)
  {
    const unsigned char* src = (const unsigned char*)wpfrag;
    #pragma unroll
    for (int it = 0; it < 16; ++it) {
      __builtin_amdgcn_global_load_lds(
          (const __attribute__((address_space(1))) unsigned int*)(src + it * 8192 + w * 1024 + l * 16),
          (__attribute__((address_space(3))) unsigned int*)(&wplds[it * 8192 + w * 1024]),
          16, 0, 0);
    }
  }

  // per-lane epilogue constants: e = et*32 + c, et = 0..7
  float bpe[8], wm2[8], Wl = 0.f;
  #pragma unroll
  for (int et = 0; et < 8; ++et) {
    float bv = bp[et * 32 + c];
    float wv = watt[et * 32 + c];
    bpe[et] = bv * C2LOG2E;
    wm2[et] = -2.f * wv;
    Wl += wv;
  }
  __syncthreads();

  const int gw = blockIdx.x * 8 + w;   // 0..2047

  for (int i = gw; i < 9216; i += 2048) {
    // ---- decode item -> (b, n, mt)  (validated R5-R17) --------------------
    int b = i / 1152;
    int r = i - b * 1152;
    int nt, cum;
    if      (r < 256)  { nt = 0; cum = 0; }
    else if (r < 480)  { nt = 1; cum = 256; }
    else if (r < 672)  { nt = 2; cum = 480; }
    else if (r < 832)  { nt = 3; cum = 672; }
    else if (r < 960)  { nt = 4; cum = 832; }
    else if (r < 1056) { nt = 5; cum = 960; }
    else               { nt = (r < 1120) ? 6 : 7; cum = (r < 1120) ? 1056 : 1120; }
    int rr = r - cum;
    int w8 = 8 - nt;                                       // divisor, 1..8
    int q0 = (int)(((unsigned)rr * kMagicDiv[w8]) >> 16);  // rr / w8
    int n  = nt * 32 + q0;
    int mt = nt + (rr - q0 * w8);                          // in [nt, 8)
    const int m0 = mt * 32;

    const unsigned char* xfb = (const unsigned char*)xfrag + (size_t)b * 131072;
    const unsigned char* xnbase = xfb + (nt << 14) + hi * 512 + q0 * 16;
    const unsigned char* xmbase = xfb + (mt << 14) + l * 16;

    // ---- full-e accumulation: acc[8] f32x16 (128 AGPR) --------------------
    f32x16 acc[8];
    #pragma unroll
    for (int et = 0; et < 8; ++et)
      #pragma unroll
      for (int q = 0; q < 16; ++q) acc[et][q] = 0.f;

    #pragma unroll 2
    for (int ks = 0; ks < 16; ++ks) {
      // transient A-frag: (x_n ∘ x_m) built per k-step, ONCE per item
      uint4 xnp = *(const uint4*)(xnbase + (ks << 10));
      uint4 xm  = *(const uint4*)(xmbase + (ks << 10));
      union U { uint4 u; short8 s; __hip_bfloat162 hh[4]; } a, mm, nn;
      mm.u = xm; nn.u = xnp;
      #pragma unroll
      for (int d = 0; d < 4; ++d) a.hh[d] = __hmul2(mm.hh[d], nn.hh[d]);

      #pragma unroll
      for (int et = 0; et < 8; ++et) {
        short8 bf = *(const short8*)(&wplds[((et * 16 + ks) << 10) + l * 16]);
        acc[et] = __builtin_amdgcn_mfma_f32_32x32x16_bf16(a.s, bf, acc[et], 0, 0, 0);
      }
    }

    // ---- epilogue: p[m] = Wl + sum_et wm2*rcp(1+exp2(acc*C + bpe)) --------
    float p[16];
    #pragma unroll
    for (int q = 0; q < 16; ++q) {
      float pq = Wl;
      #pragma unroll
      for (int et = 0; et < 8; ++et) {
        float v = fmaf(acc[et][q], C2LOG2E, bpe[et]);
        pq = fmaf(wm2[et], __builtin_amdgcn_rcpf(1.f + exp2f(v)), pq);
      }
      p[q] = pq;
    }

    // ---- reduce over 32 e-cols: 4 DPP stages + 1 shfl ---------------------
    #pragma unroll
    for (int q = 0; q < 16; ++q) {
      float v = p[q];
      v = dpp_add<DPP_XOR1>(v);
      v = dpp_add<DPP_XOR2>(v);
      v = dpp_add<DPP_XOR4>(v);
      v = dpp_add<DPP_XOR8>(v);
      v += __shfl_xor(v, 16);
      p[q] = v;
    }
    if (c == 0) {
      float* outrow = sp + (size_t)(b * 256 + n) * 256 + m0;
      #pragma unroll
      for (int q = 0; q < 16; ++q) {
        int mr = (q & 3) + 8 * (q >> 2) + 4 * hi;
        outrow[mr] = p[q];
      }
      if (mt > nt) {
        #pragma unroll
        for (int q = 0; q < 16; ++q) {
          int mr = (q & 3) + 8 * (q >> 2) + 4 * hi;
          sp[(size_t)(b * 256 + m0 + mr) * 256 + n] = p[q];
        }
      }
    }
  }
}

// -------------------------------------------------------------- colstats ----
// Per-(b,m) column max M and 1/sum(exp(s-M)) over n.  Same tile structure as
// the old softmax, minus the normalize pass and the 2MB write-back.
__global__ __launch_bounds__(256) void k_colstats(const float* __restrict__ sp,
                                                  float* __restrict__ colM,
                                                  float* __restrict__ colInv) {
  __shared__ float tile[256][33];
  __shared__ float red[8][32];
  const int t = threadIdx.x;
  const int bb = blockIdx.x >> 3, mt = blockIdx.x & 7;
  const int m0 = mt * 32;
  const int col = t & 31, g = t >> 5;   // g in [0,8)

  for (int cc = 0; cc < 32; ++cc) {
    int nn = cc * 8 + g;
    tile[nn][col] = sp[(size_t)(bb * 256 + nn) * 256 + m0 + col];
  }
  __syncthreads();
  float mx = -1e30f;
  for (int k2 = 0; k2 < 32; ++k2) mx = fmaxf(mx, tile[g * 32 + k2][col]);
  red[g][col] = mx;
  __syncthreads();
  float M = red[0][col];
  #pragma unroll
  for (int j = 1; j < 8; ++j) M = fmaxf(M, red[j][col]);
  float sm = 0.f;
  for (int k2 = 0; k2 < 32; ++k2) sm += __expf(tile[g * 32 + k2][col] - M);
  __syncthreads();
  red[g][col] = sm;
  __syncthreads();
  if (g == 0) {
    float S = red[0][col];
    #pragma unroll
    for (int j = 1; j < 8; ++j) S += red[j][col];
    colM[bb * 256 + m0 + col]   = M;
    colInv[bb * 256 + m0 + col] = 1.0f / S;
  }
}

// -------------------------------------------------------------- aggproj -----
// att computed on the fly: att[n,m] = exp(sp[n,m]-M_m)*inv_m.  Then
// out[n,e] = (att[n,:] @ x_b) @ W1 + x_n @ W2 + b1 + b2; BN partial sums into
// bnacc via atomics (bnacc zeroed by k_prep).
__global__ __launch_bounds__(256) void k_aggproj(
    const float* __restrict__ x, const float* __restrict__ spRaw,
    const float* __restrict__ colM, const float* __restrict__ colInv,
    const float* __restrict__ W1, const float* __restrict__ b1,
    const float* __restrict__ W2, const float* __restrict__ b2,
    float* __restrict__ out, float* __restrict__ bnacc) {
  __shared__ float att8[8][256];
  __shared__ float xn8[8][256];
  __shared__ float agg8[8][256];
  const int t = threadIdx.x;
  const int bb = blockIdx.x >> 5, ng = blockIdx.x & 31;
  const int n0 = ng * 8;

  const float cm = colM[bb * 256 + t];
  const float ci = colInv[bb * 256 + t];
  #pragma unroll
  for (int i = 0; i < 8; ++i) {
    float s = spRaw[(size_t)(bb * 256 + n0 + i) * 256 + t];
    att8[i][t] = __expf(s - cm) * ci;
    xn8[i][t]  = x[(size_t)(bb * 256 + n0 + i) * 256 + t];
  }
  __syncthreads();

  float ar[8] = {0.f, 0.f, 0.f, 0.f, 0.f, 0.f, 0.f, 0.f};
  for (int m4 = 0; m4 < 64; ++m4) {
    int m = m4 * 4;
    float xv0 = x[(size_t)(bb * 256 + m + 0) * 256 + t];
    float xv1 = x[(size_t)(bb * 256 + m + 1) * 256 + t];
    float xv2 = x[(size_t)(bb * 256 + m + 2) * 256 + t];
    float xv3 = x[(size_t)(bb * 256 + m + 3) * 256 + t];
    #pragma unroll
    for (int i = 0; i < 8; ++i) {
      float4 av = *(const float4*)&att8[i][m];
      ar[i] += av.x * xv0 + av.y * xv1 + av.z * xv2 + av.w * xv3;
    }
  }
  #pragma unroll
  for (int i = 0; i < 8; ++i) agg8[i][t] = ar[i];
  __syncthreads();

  float o[8];
  float bsum = b1[t] + b2[t];
  #pragma unroll
  for (int i = 0; i < 8; ++i) o[i] = bsum;
  for (int d4 = 0; d4 < 64; ++d4) {
    int d = d4 * 4;
    float w10 = W1[(d + 0) * 256 + t], w11 = W1[(d + 1) * 256 + t];
    float w12 = W1[(d + 2) * 256 + t], w13 = W1[(d + 3) * 256 + t];
    float w20 = W2[(d + 0) * 256 + t], w21 = W2[(d + 1) * 256 + t];
    float w22 = W2[(d + 2) * 256 + t], w23 = W2[(d + 3) * 256 + t];
    #pragma unroll
    for (int i = 0; i < 8; ++i) {
      float4 ag = *(const float4*)&agg8[i][d];
      float4 xn = *(const float4*)&xn8[i][d];
      o[i] += ag.x * w10 + ag.y * w11 + ag.z * w12 + ag.w * w13
            + xn.x * w20 + xn.y * w21 + xn.z * w22 + xn.w * w23;
    }
  }
  float s1 = 0.f, s2 = 0.f;
  #pragma unroll
  for (int i = 0; i < 8; ++i) {
    out[(size_t)(bb * 256 + n0 + i) * 256 + t] = o[i];
    s1 += o[i];
    s2 += o[i] * o[i];
  }
  atomicAdd(&bnacc[t], s1);
  atomicAdd(&bnacc[256 + t], s2);
}

// -------------------------------------------------------------- bnapply -----
__global__ __launch_bounds__(256) void k_bnapply(float* __restrict__ io,
                                                 const float* __restrict__ bnacc,
                                                 const float* __restrict__ gamma,
                                                 const float* __restrict__ beta) {
  const int e = threadIdx.x;
  float mean = bnacc[e] * (1.0f / 2048.0f);
  float var  = bnacc[256 + e] * (1.0f / 2048.0f) - mean * mean;
  float scl  = rsqrtf(var + 1e-5f) * gamma[e];
  float sh   = beta[e] - mean * scl;
  for (int r = blockIdx.x; r < 2048; r += gridDim.x) {
    float v = io[(size_t)r * 256 + e];
    float y = v * scl + sh;
    float s = (y > 0.f) ? 1.0507009873554805f * y
                        : 1.7580993408473766f * (__expf(y) - 1.0f);
    io[(size_t)r * 256 + e] = s;
  }
}

// ---------------------------------------------------------------------------
extern "C" void kernel_launch(void* const* d_in, const int* in_sizes, int n_in,
                              void* d_out, int out_size, void* d_ws, size_t ws_size,
                              hipStream_t stream) {
  const float* x     = (const float*)d_in[0];
  const float* Wp    = (const float*)d_in[1];
  const float* bp    = (const float*)d_in[2];
  const float* watt  = (const float*)d_in[3];
  const float* W1    = (const float*)d_in[4];
  const float* b1    = (const float*)d_in[5];
  const float* W2    = (const float*)d_in[6];
  const float* b2    = (const float*)d_in[7];
  const float* gamma = (const float*)d_in[8];
  const float* beta  = (const float*)d_in[9];
  float* out = (float*)d_out;
  float* ws  = (float*)d_ws;

  float* sp = ws;                                       // 524288 f32 raw scores
  unsigned int* wpfragG = (unsigned int*)(ws + 524288); // 32768 dwords (128 KB)
  unsigned int* xfragG  = wpfragG + 32768;              // 262144 dwords (1 MB)
  float* bnacc  = (float*)(xfragG + 262144);            // 512 f32
  float* colM   = bnacc + 512;                          // 2048 f32
  float* colInv = colM + 2048;                          // 2048 f32

  k_prep    <<<1152, 256, 0, stream>>>(x, Wp, xfragG, wpfragG, bnacc);
  k_scores  <<<256,  512, 0, stream>>>(xfragG, wpfragG, bp, watt, sp);
  k_colstats<<<64,   256, 0, stream>>>(sp, colM, colInv);
  k_aggproj <<<256,  256, 0, stream>>>(x, sp, colM, colInv, W1, b1, W2, b2, out, bnacc);
  k_bnapply <<<256,  256, 0, stream>>>(out, bnacc, gamma, beta);
}